// Round 1
// baseline (610.186 us; speedup 1.0000x reference)
//
#include <hip/hip_runtime.h>

#define NND 100000
#define NE  1600000
#define ET  (NE + NND)      // 1,700,000 edges incl. self loops
#define HD  128
#define NGR 64
#define NEG 0.2f

// ---------------- GEMM: h = x @ W (f32, LDS tiled) ----------------
// block: 256 thr; tile: 64 rows x 64 cols (col-half), 4x4 register tile
__global__ __launch_bounds__(256) void k_gemm(const float* __restrict__ x,
                                              const float* __restrict__ W,
                                              float* __restrict__ h) {
  __shared__ float Wl[128 * 68];   // [k][j] pitch 68 (64 cols + pad)
  __shared__ float xs[64 * 132];   // [r][k] pitch 132 (128 k + pad)
  const int t = threadIdx.x;
  const int chunk = blockIdx.x >> 1;
  const int ch = (blockIdx.x & 1) * 64;
  const int rbase = chunk * 64;
#pragma unroll
  for (int i = 0; i < 32; ++i) {
    int idx = i * 256 + t;
    int k = idx >> 6, j = idx & 63;
    Wl[k * 68 + j] = W[k * 128 + ch + j];
  }
#pragma unroll
  for (int i = 0; i < 32; ++i) {
    int idx = i * 256 + t;
    int rl = idx >> 7, k = idx & 127;
    int r = rbase + rl;
    xs[rl * 132 + k] = (r < NND) ? x[r * 128 + k] : 0.f;
  }
  __syncthreads();
  const int jg = t & 15, rg = t >> 4;
  const int j0 = jg * 4, r0 = rg * 4;
  float acc[4][4] = {};
  for (int k = 0; k < 128; k += 4) {
    float4 xv[4], wv[4];
#pragma unroll
    for (int i = 0; i < 4; ++i) xv[i] = *(const float4*)&xs[(r0 + i) * 132 + k];
#pragma unroll
    for (int kk = 0; kk < 4; ++kk) wv[kk] = *(const float4*)&Wl[(k + kk) * 68 + j0];
#pragma unroll
    for (int i = 0; i < 4; ++i) {
      float xk[4] = {xv[i].x, xv[i].y, xv[i].z, xv[i].w};
#pragma unroll
      for (int kk = 0; kk < 4; ++kk) {
        acc[i][0] = fmaf(xk[kk], wv[kk].x, acc[i][0]);
        acc[i][1] = fmaf(xk[kk], wv[kk].y, acc[i][1]);
        acc[i][2] = fmaf(xk[kk], wv[kk].z, acc[i][2]);
        acc[i][3] = fmaf(xk[kk], wv[kk].w, acc[i][3]);
      }
    }
  }
#pragma unroll
  for (int i = 0; i < 4; ++i) {
    int r = rbase + r0 + i;
    if (r < NND) {
      float4 o = make_float4(acc[i][0], acc[i][1], acc[i][2], acc[i][3]);
      *(float4*)&h[r * 128 + ch + j0] = o;
    }
  }
}

// ---------------- a_s = h@att_src, a_d = h@att_dst (wave per node) ----------------
__global__ __launch_bounds__(256) void k_dots(const float* __restrict__ h,
                                              const float* __restrict__ att_src,
                                              const float* __restrict__ att_dst,
                                              float* __restrict__ a_s,
                                              float* __restrict__ a_d) {
  int wid = (blockIdx.x * 256 + threadIdx.x) >> 6;
  int lane = threadIdx.x & 63;
  if (wid >= NND) return;
  float2 v = *(const float2*)&h[(size_t)wid * HD + lane * 2];
  float2 as = *(const float2*)&att_src[lane * 2];
  float2 ad = *(const float2*)&att_dst[lane * 2];
  float da = v.x * as.x + v.y * as.y;
  float db = v.x * ad.x + v.y * ad.y;
  for (int o = 32; o; o >>= 1) {
    da += __shfl_xor(da, o);
    db += __shfl_xor(db, o);
  }
  if (lane == 0) { a_s[wid] = da; a_d[wid] = db; }
}

// ---------------- degree count (incl self loops) ----------------
__global__ void k_deg(const int* __restrict__ ei, int* __restrict__ deg) {
  int e = blockIdx.x * 256 + threadIdx.x;
  if (e >= ET) return;
  int d = (e < NE) ? ei[NE + e] : (e - NE);
  atomicAdd(&deg[d], 1);
}

// ---------------- exclusive scan of deg -> off (3 kernels) ----------------
__global__ __launch_bounds__(256) void k_scan1(const int* __restrict__ deg,
                                               int* __restrict__ off,
                                               int* __restrict__ bsum) {
  __shared__ int sm[2][256];
  int t = threadIdx.x;
  int i = blockIdx.x * 256 + t;
  int v = (i < NND) ? deg[i] : 0;
  sm[0][t] = v;
  __syncthreads();
  int c = 0;
  for (int o = 1; o < 256; o <<= 1) {
    int val = sm[c][t];
    if (t >= o) val += sm[c][t - o];
    sm[c ^ 1][t] = val;
    c ^= 1;
    __syncthreads();
  }
  int incl = sm[c][t];
  if (i < NND) off[i] = incl - v;
  if (t == 255) bsum[blockIdx.x] = incl;
}

__global__ __launch_bounds__(512) void k_scan2(int* __restrict__ bsum) {
  __shared__ int sm[2][512];
  const int NB = 391;
  int t = threadIdx.x;
  int v = (t < NB) ? bsum[t] : 0;
  sm[0][t] = v;
  __syncthreads();
  int c = 0;
  for (int o = 1; o < 512; o <<= 1) {
    int val = sm[c][t];
    if (t >= o) val += sm[c][t - o];
    sm[c ^ 1][t] = val;
    c ^= 1;
    __syncthreads();
  }
  if (t < NB) bsum[t] = sm[c][t] - v;
}

__global__ void k_scan3(const int* __restrict__ bsum, int* __restrict__ off,
                        int* __restrict__ cur) {
  int i = blockIdx.x * 256 + threadIdx.x;
  if (i < NND) {
    int o = off[i] + bsum[blockIdx.x];
    off[i] = o;
    cur[i] = o;
  }
}

// ---------------- scatter edges into dst-CSR with e_val payload ----------------
__global__ void k_scatter(const int* __restrict__ ei,
                          const float* __restrict__ a_s,
                          const float* __restrict__ a_d,
                          int* __restrict__ cur,
                          int* __restrict__ esrc,
                          float* __restrict__ eval) {
  int e = blockIdx.x * 256 + threadIdx.x;
  if (e >= ET) return;
  int s, d;
  if (e < NE) { s = ei[e]; d = ei[NE + e]; } else { s = e - NE; d = s; }
  float ev = a_s[s] + a_d[d];
  ev = (ev > 0.f) ? ev : NEG * ev;
  int pos = atomicAdd(&cur[d], 1);
  esrc[pos] = s;
  eval[pos] = ev;
}

// ---------------- per-node softmax + aggregate + silu (wave per node) ----------------
__global__ __launch_bounds__(256) void k_agg(const int* __restrict__ off,
                                             const int* __restrict__ deg,
                                             const int* __restrict__ esrc,
                                             const float* __restrict__ eval,
                                             const float* __restrict__ h,
                                             const float* __restrict__ bias,
                                             float* __restrict__ gnn) {
  int wid = (blockIdx.x * 256 + threadIdx.x) >> 6;  // node = dst
  int lane = threadIdx.x & 63;
  if (wid >= NND) return;
  int start = off[wid];
  int ne = deg[wid];   // >= 1 (self loop)
  // pass 1: max
  float m = -1e30f;
  for (int i = lane; i < ne; i += 64) m = fmaxf(m, eval[start + i]);
  for (int o = 32; o; o >>= 1) m = fmaxf(m, __shfl_xor(m, o));
  // pass 1b: denom
  float s = 0.f;
  for (int i = lane; i < ne; i += 64) s += __expf(eval[start + i] - m);
  for (int o = 32; o; o >>= 1) s += __shfl_xor(s, o);
  float inv_s = 1.f / s;
  // pass 2: weighted aggregate, chunked by 64 with shfl broadcast
  float2 acc = make_float2(0.f, 0.f);
  for (int base = 0; base < ne; base += 64) {
    int i = base + lane;
    float p = 0.f;
    int src = 0;
    if (i < ne) {
      p = __expf(eval[start + i] - m);
      src = esrc[start + i];
    }
    int cnt = min(64, ne - base);
    for (int j = 0; j < cnt; ++j) {
      float alpha = __shfl(p, j) * inv_s;
      int sj = __shfl(src, j);
      float2 hv = *(const float2*)&h[(size_t)sj * HD + lane * 2];
      acc.x = fmaf(alpha, hv.x, acc.x);
      acc.y = fmaf(alpha, hv.y, acc.y);
    }
  }
  float2 bv = *(const float2*)&bias[lane * 2];
  float gx = acc.x + bv.x, gy = acc.y + bv.y;
  gx = gx / (1.f + __expf(-gx));
  gy = gy / (1.f + __expf(-gy));
  *(float2*)&gnn[(size_t)wid * HD + lane * 2] = make_float2(gx, gy);
}

// ---------------- per-graph mean pool (batch sorted -> run accumulation) ----------------
__global__ __launch_bounds__(256) void k_pool(const float* __restrict__ gnn,
                                              const int* __restrict__ batch,
                                              float* __restrict__ pooled,
                                              float* __restrict__ cnt) {
  int t = threadIdx.x;
  int j = t & 127, half = t >> 7;
  int base = blockIdx.x * 256;
  float acc = 0.f, c = 0.f;
  int curb = -1;
  for (int i = 0; i < 128; ++i) {
    int n = base + half + i * 2;
    if (n >= NND) break;
    int b = batch[n];
    if (b != curb) {
      if (curb >= 0) {
        atomicAdd(&pooled[curb * HD + j], acc);
        if (j == 0) atomicAdd(&cnt[curb], c);
      }
      curb = b; acc = 0.f; c = 0.f;
    }
    acc += gnn[(size_t)n * HD + j];
    c += 1.f;
  }
  if (curb >= 0) {
    atomicAdd(&pooled[curb * HD + j], acc);
    if (j == 0) atomicAdd(&cnt[curb], c);
  }
}

// ---------------- final: out[g] = (pooled[g]/cnt[g]) . fin_w + fin_b ----------------
__global__ void k_final(const float* __restrict__ pooled,
                        const float* __restrict__ cnt,
                        const float* __restrict__ fin_w,
                        const float* __restrict__ fin_b,
                        float* __restrict__ out) {
  int w = threadIdx.x >> 6, lane = threadIdx.x & 63;
  for (int g = w; g < NGR; g += 4) {
    float2 pv = *(const float2*)&pooled[g * HD + lane * 2];
    float2 fw = *(const float2*)&fin_w[lane * 2];
    float s = pv.x * fw.x + pv.y * fw.y;
    for (int o = 32; o; o >>= 1) s += __shfl_xor(s, o);
    if (lane == 0) out[g] = s / fmaxf(cnt[g], 1.f) + fin_b[0];
  }
}

extern "C" void kernel_launch(void* const* d_in, const int* in_sizes, int n_in,
                              void* d_out, int out_size, void* d_ws, size_t ws_size,
                              hipStream_t stream) {
  const float* x       = (const float*)d_in[0];
  const int*   ei      = (const int*)d_in[1];
  const int*   batch   = (const int*)d_in[2];
  const float* W       = (const float*)d_in[3];
  const float* att_src = (const float*)d_in[4];
  const float* att_dst = (const float*)d_in[5];
  const float* bias    = (const float*)d_in[6];
  const float* fin_w   = (const float*)d_in[7];
  const float* fin_b   = (const float*)d_in[8];
  float* out = (float*)d_out;

  const size_t NH = (size_t)NND * HD;
  float* h      = (float*)d_ws;
  float* gnn    = h + NH;
  float* a_s    = gnn + NH;
  float* a_d    = a_s + NND;
  float* eval   = a_d + NND;
  int*   esrc   = (int*)(eval + ET);
  int*   off    = esrc + ET;
  int*   cur    = off + NND;
  int*   deg    = cur + NND;
  int*   bsum   = deg + NND;
  float* pooled = (float*)(bsum + 512);
  float* cnt    = pooled + NGR * HD;

  // zero: deg | bsum | pooled | cnt (contiguous)
  hipMemsetAsync(deg, 0, (size_t)(NND + 512 + NGR * HD + NGR) * 4, stream);

  k_gemm<<<3126, 256, 0, stream>>>(x, W, h);
  k_dots<<<25000, 256, 0, stream>>>(h, att_src, att_dst, a_s, a_d);
  k_deg<<<(ET + 255) / 256, 256, 0, stream>>>(ei, deg);
  k_scan1<<<391, 256, 0, stream>>>(deg, off, bsum);
  k_scan2<<<1, 512, 0, stream>>>(bsum);
  k_scan3<<<391, 256, 0, stream>>>(bsum, off, cur);
  k_scatter<<<(ET + 255) / 256, 256, 0, stream>>>(ei, a_s, a_d, cur, esrc, eval);
  k_agg<<<25000, 256, 0, stream>>>(off, deg, esrc, eval, h, bias, gnn);
  k_pool<<<391, 256, 0, stream>>>(gnn, batch, pooled, cnt);
  k_final<<<1, 256, 0, stream>>>(pooled, cnt, fin_w, fin_b, out);
}

// Round 2
// 549.207 us; speedup vs baseline: 1.1110x; 1.1110x over previous
//
#include <hip/hip_runtime.h>

#define NND 100000
#define NE  1600000
#define ET  (NE + NND)      // 1,700,000 edges incl. self loops
#define HD  128
#define NGR 64
#define NEG 0.2f

__device__ __forceinline__ unsigned f2bf(float x) {
  unsigned u = __builtin_bit_cast(unsigned, x);
  return (u + 0x7fffu + ((u >> 16) & 1u)) >> 16;   // RNE, finite inputs
}

// ---------------- GEMM: h = x @ W, fused a_s/a_d dots, bf16 h output ----------------
// 128x128x128 one-shot tile, W + xT in LDS (128 KB), 8x8 register tile.
__global__ __launch_bounds__(256, 1) void k_gemm(const float* __restrict__ x,
                                                 const float* __restrict__ W,
                                                 const float* __restrict__ att_s,
                                                 const float* __restrict__ att_d,
                                                 unsigned* __restrict__ h_bf,
                                                 float* __restrict__ a_s,
                                                 float* __restrict__ a_d) {
  __shared__ float Wl[128 * 128];
  __shared__ float xT[128 * 128];   // [k][r ^ swz(k)]
  const int t = threadIdx.x;
  const int rbase = blockIdx.x * 128;
  // stage W (coalesced, conflict-free)
#pragma unroll
  for (int i = 0; i < 16; ++i) {
    int idx = i * 256 + t;
    int k = idx >> 5, j = (idx & 31) * 4;
    *(float4*)&Wl[k * 128 + j] = *(const float4*)&W[k * 128 + j];
  }
  // stage x transposed with 4-float XOR swizzle (write conflict 4-way only)
#pragma unroll
  for (int i = 0; i < 16; ++i) {
    int idx = i * 256 + t;
    int rl = idx >> 5, kq = idx & 31;
    int r = rbase + rl;
    float4 v = (r < NND) ? *(const float4*)&x[(size_t)r * 128 + kq * 4]
                         : make_float4(0.f, 0.f, 0.f, 0.f);
    int col = rl ^ ((kq & 7) << 2);
    xT[(kq * 4 + 0) * 128 + col] = v.x;
    xT[(kq * 4 + 1) * 128 + col] = v.y;
    xT[(kq * 4 + 2) * 128 + col] = v.z;
    xT[(kq * 4 + 3) * 128 + col] = v.w;
  }
  __syncthreads();
  const int tc = t & 15, tr = t >> 4;   // 16x16 thread grid
  float acc[8][8] = {};
#pragma unroll 4
  for (int k = 0; k < 128; ++k) {
    int ra = (4 * tr) ^ (((k >> 2) & 7) << 2);
    float4 xa = *(const float4*)&xT[k * 128 + ra];
    float4 xb = *(const float4*)&xT[k * 128 + 64 + ra];
    float4 wa = *(const float4*)&Wl[k * 128 + 4 * tc];
    float4 wb = *(const float4*)&Wl[k * 128 + 64 + 4 * tc];
    float xr[8] = {xa.x, xa.y, xa.z, xa.w, xb.x, xb.y, xb.z, xb.w};
    float wc[8] = {wa.x, wa.y, wa.z, wa.w, wb.x, wb.y, wb.z, wb.w};
#pragma unroll
    for (int i = 0; i < 8; ++i)
#pragma unroll
      for (int j = 0; j < 8; ++j) acc[i][j] = fmaf(xr[i], wc[j], acc[i][j]);
  }
  // epilogue: att dots (reduce over 16 tc lanes) + bf16 h write
  float asv[8], adv[8];
  {
    float4 a0 = *(const float4*)&att_s[4 * tc];
    float4 a1 = *(const float4*)&att_s[64 + 4 * tc];
    asv[0]=a0.x; asv[1]=a0.y; asv[2]=a0.z; asv[3]=a0.w;
    asv[4]=a1.x; asv[5]=a1.y; asv[6]=a1.z; asv[7]=a1.w;
    float4 b0 = *(const float4*)&att_d[4 * tc];
    float4 b1 = *(const float4*)&att_d[64 + 4 * tc];
    adv[0]=b0.x; adv[1]=b0.y; adv[2]=b0.z; adv[3]=b0.w;
    adv[4]=b1.x; adv[5]=b1.y; adv[6]=b1.z; adv[7]=b1.w;
  }
#pragma unroll
  for (int i = 0; i < 8; ++i) {
    int r = rbase + ((i < 4) ? (4 * tr + i) : (64 + 4 * tr + (i - 4)));
    float ps = 0.f, pd = 0.f;
#pragma unroll
    for (int j = 0; j < 8; ++j) {
      ps = fmaf(acc[i][j], asv[j], ps);
      pd = fmaf(acc[i][j], adv[j], pd);
    }
#pragma unroll
    for (int o = 1; o < 16; o <<= 1) {
      ps += __shfl_xor(ps, o);
      pd += __shfl_xor(pd, o);
    }
    if (r < NND) {
      if (tc == 0) { a_s[r] = ps; a_d[r] = pd; }
      unsigned p0 = f2bf(acc[i][0]) | (f2bf(acc[i][1]) << 16);
      unsigned p1 = f2bf(acc[i][2]) | (f2bf(acc[i][3]) << 16);
      unsigned p2 = f2bf(acc[i][4]) | (f2bf(acc[i][5]) << 16);
      unsigned p3 = f2bf(acc[i][6]) | (f2bf(acc[i][7]) << 16);
      uint2 lo = make_uint2(p0, p1), hi = make_uint2(p2, p3);
      *(uint2*)&h_bf[(size_t)r * 64 + 2 * tc] = lo;
      *(uint2*)&h_bf[(size_t)r * 64 + 32 + 2 * tc] = hi;
    }
  }
}

// ---------------- degree count (incl self loops) ----------------
__global__ void k_deg(const int* __restrict__ ei, int* __restrict__ deg) {
  int e = blockIdx.x * 256 + threadIdx.x;
  if (e >= ET) return;
  int d = (e < NE) ? ei[NE + e] : (e - NE);
  atomicAdd(&deg[d], 1);
}

// ---------------- exclusive scan of deg -> off ----------------
__global__ __launch_bounds__(256) void k_scan1(const int* __restrict__ deg,
                                               int* __restrict__ off,
                                               int* __restrict__ bsum) {
  __shared__ int sm[2][256];
  int t = threadIdx.x;
  int i = blockIdx.x * 256 + t;
  int v = (i < NND) ? deg[i] : 0;
  sm[0][t] = v;
  __syncthreads();
  int c = 0;
  for (int o = 1; o < 256; o <<= 1) {
    int val = sm[c][t];
    if (t >= o) val += sm[c][t - o];
    sm[c ^ 1][t] = val;
    c ^= 1;
    __syncthreads();
  }
  int incl = sm[c][t];
  if (i < NND) off[i] = incl - v;
  if (t == 255) bsum[blockIdx.x] = incl;
}

__global__ __launch_bounds__(512) void k_scan2(int* __restrict__ bsum) {
  __shared__ int sm[2][512];
  const int NB = 391;
  int t = threadIdx.x;
  int v = (t < NB) ? bsum[t] : 0;
  sm[0][t] = v;
  __syncthreads();
  int c = 0;
  for (int o = 1; o < 512; o <<= 1) {
    int val = sm[c][t];
    if (t >= o) val += sm[c][t - o];
    sm[c ^ 1][t] = val;
    c ^= 1;
    __syncthreads();
  }
  if (t < NB) bsum[t] = sm[c][t] - v;
}

__global__ void k_scan3(const int* __restrict__ bsum, int* __restrict__ off,
                        int* __restrict__ cur) {
  int i = blockIdx.x * 256 + threadIdx.x;
  if (i < NND) {
    int o = off[i] + bsum[blockIdx.x];
    off[i] = o;
    cur[i] = o;
  }
}

// ---------------- scatter edges into dst-CSR (src index only) ----------------
__global__ void k_scatter(const int* __restrict__ ei,
                          int* __restrict__ cur,
                          int* __restrict__ esrc) {
  int e = blockIdx.x * 256 + threadIdx.x;
  if (e >= ET) return;
  int s, d;
  if (e < NE) { s = ei[e]; d = ei[NE + e]; } else { s = e - NE; d = s; }
  int pos = atomicAdd(&cur[d], 1);
  esrc[pos] = s;
}

// ---------------- single-pass softmax-aggregate + silu (wave per node) ----------------
__global__ __launch_bounds__(256) void k_agg(const int* __restrict__ off,
                                             const int* __restrict__ deg,
                                             const int* __restrict__ esrc,
                                             const float* __restrict__ a_s,
                                             const float* __restrict__ a_d,
                                             const unsigned* __restrict__ hb,
                                             const float* __restrict__ bias,
                                             unsigned* __restrict__ gnn) {
  int wid = (blockIdx.x * 256 + threadIdx.x) >> 6;
  int lane = threadIdx.x & 63;
  if (wid >= NND) return;
  int start = off[wid];
  int ne = deg[wid];        // >= 1 (self loop)
  float adn = a_d[wid];
  float accx = 0.f, accy = 0.f, ssum = 0.f;
  for (int base = 0; base < ne; base += 64) {
    int i = base + lane;
    float ev = 0.f;
    int src = 0;
    if (i < ne) {
      src = esrc[start + i];
      float e = a_s[src] + adn;
      e = (e > 0.f) ? e : NEG * e;
      ev = __expf(e);       // |e| bounded ~2: no max-subtraction needed
    }
    ssum += ev;
    int cnt = min(64, ne - base);
    for (int j = 0; j < cnt; ++j) {
      float p = __shfl(ev, j);
      int sj = __shfl(src, j);
      unsigned u = hb[(size_t)sj * 64 + lane];
      float lo = __builtin_bit_cast(float, u << 16);
      float hi = __builtin_bit_cast(float, u & 0xffff0000u);
      accx = fmaf(p, lo, accx);
      accy = fmaf(p, hi, accy);
    }
  }
  for (int o = 32; o; o >>= 1) ssum += __shfl_xor(ssum, o);
  float inv = 1.f / ssum;
  float2 bv = *(const float2*)&bias[lane * 2];
  float gx = accx * inv + bv.x;
  float gy = accy * inv + bv.y;
  gx = gx / (1.f + __expf(-gx));
  gy = gy / (1.f + __expf(-gy));
  gnn[(size_t)wid * 64 + lane] = f2bf(gx) | (f2bf(gy) << 16);
}

// ---------------- per-graph mean pool (batch sorted, run accumulation) ----------------
__global__ __launch_bounds__(256) void k_pool(const unsigned* __restrict__ gnn,
                                              const int* __restrict__ batch,
                                              float* __restrict__ pooled,
                                              float* __restrict__ cnt) {
  int t = threadIdx.x;
  int j2 = t & 63, strm = t >> 6;          // 4 node streams x 64 packed cols
  int base = blockIdx.x * 256;
  float ax = 0.f, ay = 0.f, c = 0.f;
  int curb = -1;
  for (int i = 0; i < 64; ++i) {
    int n = base + strm + i * 4;
    if (n >= NND) break;
    int b = batch[n];
    if (b != curb) {
      if (curb >= 0) {
        atomicAdd(&pooled[curb * HD + 2 * j2], ax);
        atomicAdd(&pooled[curb * HD + 2 * j2 + 1], ay);
        if (j2 == 0) atomicAdd(&cnt[curb], c);
      }
      curb = b; ax = 0.f; ay = 0.f; c = 0.f;
    }
    unsigned u = gnn[(size_t)n * 64 + j2];
    ax += __builtin_bit_cast(float, u << 16);
    ay += __builtin_bit_cast(float, u & 0xffff0000u);
    c += 1.f;
  }
  if (curb >= 0) {
    atomicAdd(&pooled[curb * HD + 2 * j2], ax);
    atomicAdd(&pooled[curb * HD + 2 * j2 + 1], ay);
    if (j2 == 0) atomicAdd(&cnt[curb], c);
  }
}

// ---------------- final: out[g] = (pooled[g]/cnt[g]) . fin_w + fin_b ----------------
__global__ void k_final(const float* __restrict__ pooled,
                        const float* __restrict__ cnt,
                        const float* __restrict__ fin_w,
                        const float* __restrict__ fin_b,
                        float* __restrict__ out) {
  int w = threadIdx.x >> 6, lane = threadIdx.x & 63;
  for (int g = w; g < NGR; g += 4) {
    float2 pv = *(const float2*)&pooled[g * HD + lane * 2];
    float2 fw = *(const float2*)&fin_w[lane * 2];
    float s = pv.x * fw.x + pv.y * fw.y;
    for (int o = 32; o; o >>= 1) s += __shfl_xor(s, o);
    if (lane == 0) out[g] = s / fmaxf(cnt[g], 1.f) + fin_b[0];
  }
}

extern "C" void kernel_launch(void* const* d_in, const int* in_sizes, int n_in,
                              void* d_out, int out_size, void* d_ws, size_t ws_size,
                              hipStream_t stream) {
  const float* x       = (const float*)d_in[0];
  const int*   ei      = (const int*)d_in[1];
  const int*   batch   = (const int*)d_in[2];
  const float* W       = (const float*)d_in[3];
  const float* att_src = (const float*)d_in[4];
  const float* att_dst = (const float*)d_in[5];
  const float* bias    = (const float*)d_in[6];
  const float* fin_w   = (const float*)d_in[7];
  const float* fin_b   = (const float*)d_in[8];
  float* out = (float*)d_out;

  float*    a_s  = (float*)d_ws;                       // NND
  float*    a_d  = a_s + NND;                          // NND
  unsigned* h_bf = (unsigned*)(a_d + NND);             // NND*64 (2 bf16/word)
  unsigned* gnn  = h_bf + (size_t)NND * 64;            // NND*64
  int*      esrc = (int*)(gnn + (size_t)NND * 64);     // ET
  int*      off  = esrc + ET;                          // NND
  int*      cur  = off + NND;                          // NND
  int*      deg  = cur + NND;                          // NND
  int*      bsum = deg + NND;                          // 512
  float*  pooled = (float*)(bsum + 512);               // NGR*HD
  float*    cnt  = pooled + NGR * HD;                  // NGR

  // zero: deg | bsum | pooled | cnt (contiguous)
  hipMemsetAsync(deg, 0, (size_t)(NND + 512 + NGR * HD + NGR) * 4, stream);

  k_gemm<<<(NND + 127) / 128, 256, 0, stream>>>(x, W, att_src, att_dst, h_bf, a_s, a_d);
  k_deg<<<(ET + 255) / 256, 256, 0, stream>>>(ei, deg);
  k_scan1<<<391, 256, 0, stream>>>(deg, off, bsum);
  k_scan2<<<1, 512, 0, stream>>>(bsum);
  k_scan3<<<391, 256, 0, stream>>>(bsum, off, cur);
  k_scatter<<<(ET + 255) / 256, 256, 0, stream>>>(ei, cur, esrc);
  k_agg<<<25000, 256, 0, stream>>>(off, deg, esrc, a_s, a_d, h_bf, bias, gnn);
  k_pool<<<391, 256, 0, stream>>>(gnn, batch, pooled, cnt);
  k_final<<<1, 256, 0, stream>>>(pooled, cnt, fin_w, fin_b, out);
}

// Round 3
// 524.290 us; speedup vs baseline: 1.1638x; 1.0475x over previous
//
#include <hip/hip_runtime.h>

#define NND 100000
#define NE  1600000
#define ET  (NE + NND)      // 1,700,000 edges incl. self loops
#define HD  128
#define NGR 64
#define NEG 0.2f

#define EPB   1024          // edges per scatter block
#define NBLK  ((ET + EPB - 1) / EPB)
#define WBITS 14            // dst window = 16384 nodes (~1.1 MB esrc span)
#define NPASS ((NND + (1 << WBITS) - 1) >> WBITS)

__device__ __forceinline__ unsigned f2bf(float x) {
  unsigned u = __builtin_bit_cast(unsigned, x);
  return (u + 0x7fffu + ((u >> 16) & 1u)) >> 16;   // RNE, finite inputs
}

// ---------------- GEMM: h = x @ W, fused a_s/a_d dots, bf16 h output ----------------
__global__ __launch_bounds__(256, 1) void k_gemm(const float* __restrict__ x,
                                                 const float* __restrict__ W,
                                                 const float* __restrict__ att_s,
                                                 const float* __restrict__ att_d,
                                                 unsigned* __restrict__ h_bf,
                                                 float* __restrict__ a_s,
                                                 float* __restrict__ a_d) {
  __shared__ float Wl[128 * 128];
  __shared__ float xT[128 * 128];   // [k][r ^ swz(k)]
  const int t = threadIdx.x;
  const int rbase = blockIdx.x * 128;
#pragma unroll
  for (int i = 0; i < 16; ++i) {
    int idx = i * 256 + t;
    int k = idx >> 5, j = (idx & 31) * 4;
    *(float4*)&Wl[k * 128 + j] = *(const float4*)&W[k * 128 + j];
  }
#pragma unroll
  for (int i = 0; i < 16; ++i) {
    int idx = i * 256 + t;
    int rl = idx >> 5, kq = idx & 31;
    int r = rbase + rl;
    float4 v = (r < NND) ? *(const float4*)&x[(size_t)r * 128 + kq * 4]
                         : make_float4(0.f, 0.f, 0.f, 0.f);
    int col = rl ^ ((kq & 7) << 2);
    xT[(kq * 4 + 0) * 128 + col] = v.x;
    xT[(kq * 4 + 1) * 128 + col] = v.y;
    xT[(kq * 4 + 2) * 128 + col] = v.z;
    xT[(kq * 4 + 3) * 128 + col] = v.w;
  }
  __syncthreads();
  const int tc = t & 15, tr = t >> 4;
  float acc[8][8] = {};
#pragma unroll 4
  for (int k = 0; k < 128; ++k) {
    int ra = (4 * tr) ^ (((k >> 2) & 7) << 2);
    float4 xa = *(const float4*)&xT[k * 128 + ra];
    float4 xb = *(const float4*)&xT[k * 128 + 64 + ra];
    float4 wa = *(const float4*)&Wl[k * 128 + 4 * tc];
    float4 wb = *(const float4*)&Wl[k * 128 + 64 + 4 * tc];
    float xr[8] = {xa.x, xa.y, xa.z, xa.w, xb.x, xb.y, xb.z, xb.w};
    float wc[8] = {wa.x, wa.y, wa.z, wa.w, wb.x, wb.y, wb.z, wb.w};
#pragma unroll
    for (int i = 0; i < 8; ++i)
#pragma unroll
      for (int j = 0; j < 8; ++j) acc[i][j] = fmaf(xr[i], wc[j], acc[i][j]);
  }
  float asv[8], adv[8];
  {
    float4 a0 = *(const float4*)&att_s[4 * tc];
    float4 a1 = *(const float4*)&att_s[64 + 4 * tc];
    asv[0]=a0.x; asv[1]=a0.y; asv[2]=a0.z; asv[3]=a0.w;
    asv[4]=a1.x; asv[5]=a1.y; asv[6]=a1.z; asv[7]=a1.w;
    float4 b0 = *(const float4*)&att_d[4 * tc];
    float4 b1 = *(const float4*)&att_d[64 + 4 * tc];
    adv[0]=b0.x; adv[1]=b0.y; adv[2]=b0.z; adv[3]=b0.w;
    adv[4]=b1.x; adv[5]=b1.y; adv[6]=b1.z; adv[7]=b1.w;
  }
#pragma unroll
  for (int i = 0; i < 8; ++i) {
    int r = rbase + ((i < 4) ? (4 * tr + i) : (64 + 4 * tr + (i - 4)));
    float ps = 0.f, pd = 0.f;
#pragma unroll
    for (int j = 0; j < 8; ++j) {
      ps = fmaf(acc[i][j], asv[j], ps);
      pd = fmaf(acc[i][j], adv[j], pd);
    }
#pragma unroll
    for (int o = 1; o < 16; o <<= 1) {
      ps += __shfl_xor(ps, o);
      pd += __shfl_xor(pd, o);
    }
    if (r < NND) {
      if (tc == 0) { a_s[r] = ps; a_d[r] = pd; }
      unsigned p0 = f2bf(acc[i][0]) | (f2bf(acc[i][1]) << 16);
      unsigned p1 = f2bf(acc[i][2]) | (f2bf(acc[i][3]) << 16);
      unsigned p2 = f2bf(acc[i][4]) | (f2bf(acc[i][5]) << 16);
      unsigned p3 = f2bf(acc[i][6]) | (f2bf(acc[i][7]) << 16);
      uint2 lo = make_uint2(p0, p1), hi = make_uint2(p2, p3);
      *(uint2*)&h_bf[(size_t)r * 64 + 2 * tc] = lo;
      *(uint2*)&h_bf[(size_t)r * 64 + 32 + 2 * tc] = hi;
    }
  }
}

// ---------------- degree count (incl self loops) ----------------
__global__ void k_deg(const int* __restrict__ ei, int* __restrict__ deg) {
  int e = blockIdx.x * 256 + threadIdx.x;
  if (e >= ET) return;
  int d = (e < NE) ? ei[NE + e] : (e - NE);
  atomicAdd(&deg[d], 1);
}

// ---------------- exclusive scan of deg -> off ----------------
__global__ __launch_bounds__(256) void k_scan1(const int* __restrict__ deg,
                                               int* __restrict__ off,
                                               int* __restrict__ bsum) {
  __shared__ int sm[2][256];
  int t = threadIdx.x;
  int i = blockIdx.x * 256 + t;
  int v = (i < NND) ? deg[i] : 0;
  sm[0][t] = v;
  __syncthreads();
  int c = 0;
  for (int o = 1; o < 256; o <<= 1) {
    int val = sm[c][t];
    if (t >= o) val += sm[c][t - o];
    sm[c ^ 1][t] = val;
    c ^= 1;
    __syncthreads();
  }
  int incl = sm[c][t];
  if (i < NND) off[i] = incl - v;
  if (t == 255) bsum[blockIdx.x] = incl;
}

__global__ __launch_bounds__(512) void k_scan2(int* __restrict__ bsum) {
  __shared__ int sm[2][512];
  const int NB = 391;
  int t = threadIdx.x;
  int v = (t < NB) ? bsum[t] : 0;
  sm[0][t] = v;
  __syncthreads();
  int c = 0;
  for (int o = 1; o < 512; o <<= 1) {
    int val = sm[c][t];
    if (t >= o) val += sm[c][t - o];
    sm[c ^ 1][t] = val;
    c ^= 1;
    __syncthreads();
  }
  if (t < NB) bsum[t] = sm[c][t] - v;
}

__global__ void k_scan3(const int* __restrict__ bsum, int* __restrict__ off,
                        int* __restrict__ cur) {
  int i = blockIdx.x * 256 + threadIdx.x;
  if (i < NND) {
    int o = off[i] + bsum[blockIdx.x];
    off[i] = o;
    cur[i] = o;
  }
}

// ---------------- windowed scatter: confine concurrent writes to ~1.1 MB ----------------
__global__ __launch_bounds__(256) void k_scatter(const int* __restrict__ ei,
                                                 int* __restrict__ cur,
                                                 int* __restrict__ esrc) {
  __shared__ int ss[EPB], sd[EPB];
  const int t = threadIdx.x;
  const int base = blockIdx.x * EPB;
#pragma unroll
  for (int i = 0; i < EPB / 256; ++i) {
    int e = base + i * 256 + t;
    int s = 0, d = 0x7fffffff;            // sentinel: matches no window
    if (e < NE) { s = ei[e]; d = ei[NE + e]; }
    else if (e < ET) { s = e - NE; d = s; }
    ss[i * 256 + t] = s;
    sd[i * 256 + t] = d;
  }
  __syncthreads();
  for (int p = 0; p < NPASS; ++p) {
    for (int i = t; i < EPB; i += 256) {
      int d = sd[i];
      if ((d >> WBITS) == p) {
        int pos = atomicAdd(&cur[d], 1);
        esrc[pos] = ss[i];
      }
    }
  }
}

// ---------------- single-pass softmax-aggregate + silu (wave per node) ----------------
__global__ __launch_bounds__(256) void k_agg(const int* __restrict__ off,
                                             const int* __restrict__ deg,
                                             const int* __restrict__ esrc,
                                             const float* __restrict__ a_s,
                                             const float* __restrict__ a_d,
                                             const unsigned* __restrict__ hb,
                                             const float* __restrict__ bias,
                                             unsigned* __restrict__ gnn) {
  int wid = (blockIdx.x * 256 + threadIdx.x) >> 6;
  int lane = threadIdx.x & 63;
  if (wid >= NND) return;
  int start = off[wid];
  int ne = deg[wid];        // >= 1 (self loop)
  float adn = a_d[wid];
  float accx = 0.f, accy = 0.f, ssum = 0.f;
  for (int base = 0; base < ne; base += 64) {
    int i = base + lane;
    float ev = 0.f;
    int src = 0;
    if (i < ne) {
      src = esrc[start + i];
      float e = a_s[src] + adn;
      e = (e > 0.f) ? e : NEG * e;
      ev = __expf(e);       // |e| bounded: no max-subtraction needed
    }
    ssum += ev;
    int cnt = min(64, ne - base);
    for (int j = 0; j < cnt; ++j) {
      float p = __shfl(ev, j);
      int sj = __shfl(src, j);
      unsigned u = hb[(size_t)sj * 64 + lane];
      float lo = __builtin_bit_cast(float, u << 16);
      float hi = __builtin_bit_cast(float, u & 0xffff0000u);
      accx = fmaf(p, lo, accx);
      accy = fmaf(p, hi, accy);
    }
  }
  for (int o = 32; o; o >>= 1) ssum += __shfl_xor(ssum, o);
  float inv = 1.f / ssum;
  float2 bv = *(const float2*)&bias[lane * 2];
  float gx = accx * inv + bv.x;
  float gy = accy * inv + bv.y;
  gx = gx / (1.f + __expf(-gx));
  gy = gy / (1.f + __expf(-gy));
  gnn[(size_t)wid * 64 + lane] = f2bf(gx) | (f2bf(gy) << 16);
}

// ---------------- per-graph mean pool (batch sorted, run accumulation) ----------------
__global__ __launch_bounds__(256) void k_pool(const unsigned* __restrict__ gnn,
                                              const int* __restrict__ batch,
                                              float* __restrict__ pooled,
                                              float* __restrict__ cnt) {
  int t = threadIdx.x;
  int j2 = t & 63, strm = t >> 6;
  int base = blockIdx.x * 256;
  float ax = 0.f, ay = 0.f, c = 0.f;
  int curb = -1;
  for (int i = 0; i < 64; ++i) {
    int n = base + strm + i * 4;
    if (n >= NND) break;
    int b = batch[n];
    if (b != curb) {
      if (curb >= 0) {
        atomicAdd(&pooled[curb * HD + 2 * j2], ax);
        atomicAdd(&pooled[curb * HD + 2 * j2 + 1], ay);
        if (j2 == 0) atomicAdd(&cnt[curb], c);
      }
      curb = b; ax = 0.f; ay = 0.f; c = 0.f;
    }
    unsigned u = gnn[(size_t)n * 64 + j2];
    ax += __builtin_bit_cast(float, u << 16);
    ay += __builtin_bit_cast(float, u & 0xffff0000u);
    c += 1.f;
  }
  if (curb >= 0) {
    atomicAdd(&pooled[curb * HD + 2 * j2], ax);
    atomicAdd(&pooled[curb * HD + 2 * j2 + 1], ay);
    if (j2 == 0) atomicAdd(&cnt[curb], c);
  }
}

// ---------------- final ----------------
__global__ void k_final(const float* __restrict__ pooled,
                        const float* __restrict__ cnt,
                        const float* __restrict__ fin_w,
                        const float* __restrict__ fin_b,
                        float* __restrict__ out) {
  int w = threadIdx.x >> 6, lane = threadIdx.x & 63;
  for (int g = w; g < NGR; g += 4) {
    float2 pv = *(const float2*)&pooled[g * HD + lane * 2];
    float2 fw = *(const float2*)&fin_w[lane * 2];
    float s = pv.x * fw.x + pv.y * fw.y;
    for (int o = 32; o; o >>= 1) s += __shfl_xor(s, o);
    if (lane == 0) out[g] = s / fmaxf(cnt[g], 1.f) + fin_b[0];
  }
}

extern "C" void kernel_launch(void* const* d_in, const int* in_sizes, int n_in,
                              void* d_out, int out_size, void* d_ws, size_t ws_size,
                              hipStream_t stream) {
  const float* x       = (const float*)d_in[0];
  const int*   ei      = (const int*)d_in[1];
  const int*   batch   = (const int*)d_in[2];
  const float* W       = (const float*)d_in[3];
  const float* att_src = (const float*)d_in[4];
  const float* att_dst = (const float*)d_in[5];
  const float* bias    = (const float*)d_in[6];
  const float* fin_w   = (const float*)d_in[7];
  const float* fin_b   = (const float*)d_in[8];
  float* out = (float*)d_out;

  float*    a_s  = (float*)d_ws;                       // NND
  float*    a_d  = a_s + NND;                          // NND
  unsigned* h_bf = (unsigned*)(a_d + NND);             // NND*64
  unsigned* gnn  = h_bf + (size_t)NND * 64;            // NND*64
  int*      esrc = (int*)(gnn + (size_t)NND * 64);     // ET
  int*      off  = esrc + ET;                          // NND
  int*      cur  = off + NND;                          // NND
  int*      deg  = cur + NND;                          // NND
  int*      bsum = deg + NND;                          // 512
  float*  pooled = (float*)(bsum + 512);               // NGR*HD
  float*    cnt  = pooled + NGR * HD;                  // NGR

  hipMemsetAsync(deg, 0, (size_t)(NND + 512 + NGR * HD + NGR) * 4, stream);

  k_gemm<<<(NND + 127) / 128, 256, 0, stream>>>(x, W, att_src, att_dst, h_bf, a_s, a_d);
  k_deg<<<(ET + 255) / 256, 256, 0, stream>>>(ei, deg);
  k_scan1<<<391, 256, 0, stream>>>(deg, off, bsum);
  k_scan2<<<1, 512, 0, stream>>>(bsum);
  k_scan3<<<391, 256, 0, stream>>>(bsum, off, cur);
  k_scatter<<<NBLK, 256, 0, stream>>>(ei, cur, esrc);
  k_agg<<<25000, 256, 0, stream>>>(off, deg, esrc, a_s, a_d, h_bf, bias, gnn);
  k_pool<<<391, 256, 0, stream>>>(gnn, batch, pooled, cnt);
  k_final<<<1, 256, 0, stream>>>(pooled, cnt, fin_w, fin_b, out);
}

// Round 4
// 467.066 us; speedup vs baseline: 1.3064x; 1.1225x over previous
//
#include <hip/hip_runtime.h>

#define NND 100000
#define NE  1600000
#define ET  (NE + NND)      // 1,700,000 edges incl. self loops
#define HD  128
#define NGR 64
#define NEG 0.2f

#define EPB   1024          // edges per scatter block
#define NBLK  ((ET + EPB - 1) / EPB)
#define WBITS 14            // dst window = 16384 nodes (~1.1 MB esrc span)
#define NPASS ((NND + (1 << WBITS) - 1) >> WBITS)

__device__ __forceinline__ unsigned f2bf(float x) {
  unsigned u = __builtin_bit_cast(unsigned, x);
  return (u + 0x7fffu + ((u >> 16) & 1u)) >> 16;   // RNE, finite inputs
}
__device__ __forceinline__ float bflo(unsigned u) { return __builtin_bit_cast(float, u << 16); }
__device__ __forceinline__ float bfhi(unsigned u) { return __builtin_bit_cast(float, u & 0xffff0000u); }

// ---------------- GEMM: h = x @ W, fused a_s/a_d dots, bf16 h output ----------------
// 128x128x128 tile, 512 threads (2 waves/SIMD), 4x8 register tile.
__global__ __launch_bounds__(512, 1) void k_gemm(const float* __restrict__ x,
                                                 const float* __restrict__ W,
                                                 const float* __restrict__ att_s,
                                                 const float* __restrict__ att_d,
                                                 unsigned* __restrict__ h_bf,
                                                 float* __restrict__ a_s,
                                                 float* __restrict__ a_d) {
  __shared__ float Wl[128 * 128];
  __shared__ float xT[128 * 128];   // [k][r ^ swz(k)]
  const int t = threadIdx.x;
  const int rbase = blockIdx.x * 128;
#pragma unroll
  for (int i = 0; i < 8; ++i) {
    int idx = i * 512 + t;
    int k = idx >> 5, j = (idx & 31) * 4;
    *(float4*)&Wl[k * 128 + j] = *(const float4*)&W[k * 128 + j];
  }
#pragma unroll
  for (int i = 0; i < 8; ++i) {
    int idx = i * 512 + t;
    int rl = idx >> 5, kq = idx & 31;
    int r = rbase + rl;
    float4 v = (r < NND) ? *(const float4*)&x[(size_t)r * 128 + kq * 4]
                         : make_float4(0.f, 0.f, 0.f, 0.f);
    int col = rl ^ ((kq & 7) << 2);
    xT[(kq * 4 + 0) * 128 + col] = v.x;
    xT[(kq * 4 + 1) * 128 + col] = v.y;
    xT[(kq * 4 + 2) * 128 + col] = v.z;
    xT[(kq * 4 + 3) * 128 + col] = v.w;
  }
  __syncthreads();
  const int tc = t & 15, tr = t >> 4;   // tc 0..15 cols, tr 0..31 rows
  float acc[4][8] = {};
#pragma unroll 4
  for (int k = 0; k < 128; ++k) {
    int ra = (4 * tr) ^ (((k >> 2) & 7) << 2);
    float4 xa = *(const float4*)&xT[k * 128 + ra];
    float4 wa = *(const float4*)&Wl[k * 128 + 4 * tc];
    float4 wb = *(const float4*)&Wl[k * 128 + 64 + 4 * tc];
    float xr[4] = {xa.x, xa.y, xa.z, xa.w};
    float wc[8] = {wa.x, wa.y, wa.z, wa.w, wb.x, wb.y, wb.z, wb.w};
#pragma unroll
    for (int i = 0; i < 4; ++i)
#pragma unroll
      for (int j = 0; j < 8; ++j) acc[i][j] = fmaf(xr[i], wc[j], acc[i][j]);
  }
  float asv[8], adv[8];
  {
    float4 a0 = *(const float4*)&att_s[4 * tc];
    float4 a1 = *(const float4*)&att_s[64 + 4 * tc];
    asv[0]=a0.x; asv[1]=a0.y; asv[2]=a0.z; asv[3]=a0.w;
    asv[4]=a1.x; asv[5]=a1.y; asv[6]=a1.z; asv[7]=a1.w;
    float4 b0 = *(const float4*)&att_d[4 * tc];
    float4 b1 = *(const float4*)&att_d[64 + 4 * tc];
    adv[0]=b0.x; adv[1]=b0.y; adv[2]=b0.z; adv[3]=b0.w;
    adv[4]=b1.x; adv[5]=b1.y; adv[6]=b1.z; adv[7]=b1.w;
  }
#pragma unroll
  for (int i = 0; i < 4; ++i) {
    int r = rbase + 4 * tr + i;
    float ps = 0.f, pd = 0.f;
#pragma unroll
    for (int j = 0; j < 8; ++j) {
      ps = fmaf(acc[i][j], asv[j], ps);
      pd = fmaf(acc[i][j], adv[j], pd);
    }
#pragma unroll
    for (int o = 1; o < 16; o <<= 1) {
      ps += __shfl_xor(ps, o);
      pd += __shfl_xor(pd, o);
    }
    if (r < NND) {
      if (tc == 0) { a_s[r] = ps; a_d[r] = pd; }
      unsigned p0 = f2bf(acc[i][0]) | (f2bf(acc[i][1]) << 16);
      unsigned p1 = f2bf(acc[i][2]) | (f2bf(acc[i][3]) << 16);
      unsigned p2 = f2bf(acc[i][4]) | (f2bf(acc[i][5]) << 16);
      unsigned p3 = f2bf(acc[i][6]) | (f2bf(acc[i][7]) << 16);
      *(uint2*)&h_bf[(size_t)r * 64 + 2 * tc] = make_uint2(p0, p1);
      *(uint2*)&h_bf[(size_t)r * 64 + 32 + 2 * tc] = make_uint2(p2, p3);
    }
  }
}

// ---------------- degree count (incl self loops) ----------------
__global__ void k_deg(const int* __restrict__ ei, int* __restrict__ deg) {
  int e = blockIdx.x * 256 + threadIdx.x;
  if (e >= ET) return;
  int d = (e < NE) ? ei[NE + e] : (e - NE);
  atomicAdd(&deg[d], 1);
}

// ---------------- exclusive scan of deg -> off ----------------
__global__ __launch_bounds__(256) void k_scan1(const int* __restrict__ deg,
                                               int* __restrict__ off,
                                               int* __restrict__ bsum) {
  __shared__ int sm[2][256];
  int t = threadIdx.x;
  int i = blockIdx.x * 256 + t;
  int v = (i < NND) ? deg[i] : 0;
  sm[0][t] = v;
  __syncthreads();
  int c = 0;
  for (int o = 1; o < 256; o <<= 1) {
    int val = sm[c][t];
    if (t >= o) val += sm[c][t - o];
    sm[c ^ 1][t] = val;
    c ^= 1;
    __syncthreads();
  }
  int incl = sm[c][t];
  if (i < NND) off[i] = incl - v;
  if (t == 255) bsum[blockIdx.x] = incl;
}

__global__ __launch_bounds__(512) void k_scan2(int* __restrict__ bsum) {
  __shared__ int sm[2][512];
  const int NB = 391;
  int t = threadIdx.x;
  int v = (t < NB) ? bsum[t] : 0;
  sm[0][t] = v;
  __syncthreads();
  int c = 0;
  for (int o = 1; o < 512; o <<= 1) {
    int val = sm[c][t];
    if (t >= o) val += sm[c][t - o];
    sm[c ^ 1][t] = val;
    c ^= 1;
    __syncthreads();
  }
  if (t < NB) bsum[t] = sm[c][t] - v;
}

__global__ void k_scan3(const int* __restrict__ bsum, int* __restrict__ off,
                        int* __restrict__ cur) {
  int i = blockIdx.x * 256 + threadIdx.x;
  if (i < NND) {
    int o = off[i] + bsum[blockIdx.x];
    off[i] = o;
    cur[i] = o;
  }
}

// ---------------- windowed scatter: confine concurrent writes to ~1.1 MB ----------------
__global__ __launch_bounds__(256) void k_scatter(const int* __restrict__ ei,
                                                 int* __restrict__ cur,
                                                 int* __restrict__ esrc) {
  __shared__ int ss[EPB], sd[EPB];
  const int t = threadIdx.x;
  const int base = blockIdx.x * EPB;
#pragma unroll
  for (int i = 0; i < EPB / 256; ++i) {
    int e = base + i * 256 + t;
    int s = 0, d = 0x7fffffff;
    if (e < NE) { s = ei[e]; d = ei[NE + e]; }
    else if (e < ET) { s = e - NE; d = s; }
    ss[i * 256 + t] = s;
    sd[i * 256 + t] = d;
  }
  __syncthreads();
  for (int p = 0; p < NPASS; ++p) {
    for (int i = t; i < EPB; i += 256) {
      int d = sd[i];
      if ((d >> WBITS) == p) {
        int pos = atomicAdd(&cur[d], 1);
        esrc[pos] = ss[i];
      }
    }
  }
}

// ---------------- single-pass softmax-aggregate + silu ----------------
// wave per node; 4 edge-slots x 16 col-lanes -> 4 rows gathered per load instr
__global__ __launch_bounds__(256) void k_agg(const int* __restrict__ off,
                                             const int* __restrict__ deg,
                                             const int* __restrict__ esrc,
                                             const float* __restrict__ a_s,
                                             const float* __restrict__ a_d,
                                             const unsigned* __restrict__ hb,
                                             const float* __restrict__ bias,
                                             unsigned* __restrict__ gnn) {
  int wid = (blockIdx.x * 256 + threadIdx.x) >> 6;
  int lane = threadIdx.x & 63;
  if (wid >= NND) return;
  const int grp = lane >> 4;     // edge slot 0..3
  const int lc  = lane & 15;     // col chunk: 4 words = 8 cols
  int start = off[wid];
  int ne = deg[wid];             // >= 1 (self loop)
  float adn = a_d[wid];
  float acc[8] = {};
  float ssum = 0.f;
  for (int base = 0; base < ne; base += 64) {
    int i = base + lane;
    float ev = 0.f;
    int src = 0;
    if (i < ne) {
      src = esrc[start + i];
      float e = a_s[src] + adn;
      e = (e > 0.f) ? e : NEG * e;
      ev = __expf(e);            // |e| bounded: no max-subtraction needed
    }
    ssum += ev;
    int cnt = min(64, ne - base);
    for (int jj = 0; jj < cnt; jj += 4) {
      int idx = jj + grp;        // <= 63 always; ev==0 beyond cnt
      float p  = __shfl(ev, idx);
      int   sj = __shfl(src, idx);
      uint4 u = *((const uint4*)(hb + ((size_t)sj << 6)) + lc);
      acc[0] = fmaf(p, bflo(u.x), acc[0]);
      acc[1] = fmaf(p, bfhi(u.x), acc[1]);
      acc[2] = fmaf(p, bflo(u.y), acc[2]);
      acc[3] = fmaf(p, bfhi(u.y), acc[3]);
      acc[4] = fmaf(p, bflo(u.z), acc[4]);
      acc[5] = fmaf(p, bfhi(u.z), acc[5]);
      acc[6] = fmaf(p, bflo(u.w), acc[6]);
      acc[7] = fmaf(p, bfhi(u.w), acc[7]);
    }
  }
  for (int o = 32; o; o >>= 1) ssum += __shfl_xor(ssum, o);
#pragma unroll
  for (int r = 0; r < 8; ++r) {
    acc[r] += __shfl_xor(acc[r], 16);
    acc[r] += __shfl_xor(acc[r], 32);
  }
  if (grp == 0) {
    float inv = 1.f / ssum;
    float4 b0 = *(const float4*)&bias[lc * 8];
    float4 b1 = *(const float4*)&bias[lc * 8 + 4];
    float bb[8] = {b0.x, b0.y, b0.z, b0.w, b1.x, b1.y, b1.z, b1.w};
    float g[8];
#pragma unroll
    for (int r = 0; r < 8; ++r) {
      float v = acc[r] * inv + bb[r];
      g[r] = v / (1.f + __expf(-v));
    }
    unsigned w0 = f2bf(g[0]) | (f2bf(g[1]) << 16);
    unsigned w1 = f2bf(g[2]) | (f2bf(g[3]) << 16);
    unsigned w2 = f2bf(g[4]) | (f2bf(g[5]) << 16);
    unsigned w3 = f2bf(g[6]) | (f2bf(g[7]) << 16);
    *(uint4*)&gnn[(size_t)wid * 64 + lc * 4] = make_uint4(w0, w1, w2, w3);
  }
}

// ---------------- per-graph mean pool (batch sorted, run accumulation) ----------------
__global__ __launch_bounds__(256) void k_pool(const unsigned* __restrict__ gnn,
                                              const int* __restrict__ batch,
                                              float* __restrict__ pooled,
                                              float* __restrict__ cnt) {
  int t = threadIdx.x;
  int j2 = t & 63, strm = t >> 6;
  int base = blockIdx.x * 256;
  float ax = 0.f, ay = 0.f, c = 0.f;
  int curb = -1;
  for (int i = 0; i < 64; ++i) {
    int n = base + strm + i * 4;
    if (n >= NND) break;
    int b = batch[n];
    if (b != curb) {
      if (curb >= 0) {
        atomicAdd(&pooled[curb * HD + 2 * j2], ax);
        atomicAdd(&pooled[curb * HD + 2 * j2 + 1], ay);
        if (j2 == 0) atomicAdd(&cnt[curb], c);
      }
      curb = b; ax = 0.f; ay = 0.f; c = 0.f;
    }
    unsigned u = gnn[(size_t)n * 64 + j2];
    ax += bflo(u);
    ay += bfhi(u);
    c += 1.f;
  }
  if (curb >= 0) {
    atomicAdd(&pooled[curb * HD + 2 * j2], ax);
    atomicAdd(&pooled[curb * HD + 2 * j2 + 1], ay);
    if (j2 == 0) atomicAdd(&cnt[curb], c);
  }
}

// ---------------- final ----------------
__global__ void k_final(const float* __restrict__ pooled,
                        const float* __restrict__ cnt,
                        const float* __restrict__ fin_w,
                        const float* __restrict__ fin_b,
                        float* __restrict__ out) {
  int w = threadIdx.x >> 6, lane = threadIdx.x & 63;
  for (int g = w; g < NGR; g += 4) {
    float2 pv = *(const float2*)&pooled[g * HD + lane * 2];
    float2 fw = *(const float2*)&fin_w[lane * 2];
    float s = pv.x * fw.x + pv.y * fw.y;
    for (int o = 32; o; o >>= 1) s += __shfl_xor(s, o);
    if (lane == 0) out[g] = s / fmaxf(cnt[g], 1.f) + fin_b[0];
  }
}

extern "C" void kernel_launch(void* const* d_in, const int* in_sizes, int n_in,
                              void* d_out, int out_size, void* d_ws, size_t ws_size,
                              hipStream_t stream) {
  const float* x       = (const float*)d_in[0];
  const int*   ei      = (const int*)d_in[1];
  const int*   batch   = (const int*)d_in[2];
  const float* W       = (const float*)d_in[3];
  const float* att_src = (const float*)d_in[4];
  const float* att_dst = (const float*)d_in[5];
  const float* bias    = (const float*)d_in[6];
  const float* fin_w   = (const float*)d_in[7];
  const float* fin_b   = (const float*)d_in[8];
  float* out = (float*)d_out;

  float*    a_s  = (float*)d_ws;                       // NND
  float*    a_d  = a_s + NND;                          // NND
  unsigned* h_bf = (unsigned*)(a_d + NND);             // NND*64
  unsigned* gnn  = h_bf + (size_t)NND * 64;            // NND*64
  int*      esrc = (int*)(gnn + (size_t)NND * 64);     // ET
  int*      off  = esrc + ET;                          // NND
  int*      cur  = off + NND;                          // NND
  int*      deg  = cur + NND;                          // NND
  int*      bsum = deg + NND;                          // 512
  float*  pooled = (float*)(bsum + 512);               // NGR*HD
  float*    cnt  = pooled + NGR * HD;                  // NGR

  hipMemsetAsync(deg, 0, (size_t)(NND + 512 + NGR * HD + NGR) * 4, stream);

  k_gemm<<<(NND + 127) / 128, 512, 0, stream>>>(x, W, att_src, att_dst, h_bf, a_s, a_d);
  k_deg<<<(ET + 255) / 256, 256, 0, stream>>>(ei, deg);
  k_scan1<<<391, 256, 0, stream>>>(deg, off, bsum);
  k_scan2<<<1, 512, 0, stream>>>(bsum);
  k_scan3<<<391, 256, 0, stream>>>(bsum, off, cur);
  k_scatter<<<NBLK, 256, 0, stream>>>(ei, cur, esrc);
  k_agg<<<25000, 256, 0, stream>>>(off, deg, esrc, a_s, a_d, h_bf, bias, gnn);
  k_pool<<<391, 256, 0, stream>>>(gnn, batch, pooled, cnt);
  k_final<<<1, 256, 0, stream>>>(pooled, cnt, fin_w, fin_b, out);
}

// Round 5
// 378.197 us; speedup vs baseline: 1.6134x; 1.2350x over previous
//
#include <hip/hip_runtime.h>

#define NND 100000
#define NE  1600000
#define ET  (NE + NND)      // 1,700,000 edges incl. self loops
#define HD  128
#define NGR 64
#define NEG 0.2f

#define PEB   16384                     // edges per partition block
#define PBLK  ((ET + PEB - 1) / PEB)    // 104
#define NBK   ((NND + 511) / 512)       // 196 buckets of 512 nodes

__device__ __forceinline__ unsigned f2bf(float x) {
  unsigned u = __builtin_bit_cast(unsigned, x);
  return (u + 0x7fffu + ((u >> 16) & 1u)) >> 16;   // RNE, finite inputs
}
__device__ __forceinline__ float bflo(unsigned u) { return __builtin_bit_cast(float, u << 16); }
__device__ __forceinline__ float bfhi(unsigned u) { return __builtin_bit_cast(float, u & 0xffff0000u); }

// ---------------- GEMM: h = x @ W, fused a_s/a_d dots, bf16 h output ----------------
__global__ __launch_bounds__(512, 1) void k_gemm(const float* __restrict__ x,
                                                 const float* __restrict__ W,
                                                 const float* __restrict__ att_s,
                                                 const float* __restrict__ att_d,
                                                 unsigned* __restrict__ h_bf,
                                                 float* __restrict__ a_s,
                                                 float* __restrict__ a_d) {
  __shared__ float Wl[128 * 128];
  __shared__ float xT[128 * 128];   // [k][r ^ swz(k)]
  const int t = threadIdx.x;
  const int rbase = blockIdx.x * 128;
#pragma unroll
  for (int i = 0; i < 8; ++i) {
    int idx = i * 512 + t;
    int k = idx >> 5, j = (idx & 31) * 4;
    *(float4*)&Wl[k * 128 + j] = *(const float4*)&W[k * 128 + j];
  }
#pragma unroll
  for (int i = 0; i < 8; ++i) {
    int idx = i * 512 + t;
    int rl = idx >> 5, kq = idx & 31;
    int r = rbase + rl;
    float4 v = (r < NND) ? *(const float4*)&x[(size_t)r * 128 + kq * 4]
                         : make_float4(0.f, 0.f, 0.f, 0.f);
    int col = rl ^ ((kq & 7) << 2);
    xT[(kq * 4 + 0) * 128 + col] = v.x;
    xT[(kq * 4 + 1) * 128 + col] = v.y;
    xT[(kq * 4 + 2) * 128 + col] = v.z;
    xT[(kq * 4 + 3) * 128 + col] = v.w;
  }
  __syncthreads();
  const int tc = t & 15, tr = t >> 4;
  float acc[4][8] = {};
#pragma unroll 4
  for (int k = 0; k < 128; ++k) {
    int ra = (4 * tr) ^ (((k >> 2) & 7) << 2);
    float4 xa = *(const float4*)&xT[k * 128 + ra];
    float4 wa = *(const float4*)&Wl[k * 128 + 4 * tc];
    float4 wb = *(const float4*)&Wl[k * 128 + 64 + 4 * tc];
    float xr[4] = {xa.x, xa.y, xa.z, xa.w};
    float wc[8] = {wa.x, wa.y, wa.z, wa.w, wb.x, wb.y, wb.z, wb.w};
#pragma unroll
    for (int i = 0; i < 4; ++i)
#pragma unroll
      for (int j = 0; j < 8; ++j) acc[i][j] = fmaf(xr[i], wc[j], acc[i][j]);
  }
  float asv[8], adv[8];
  {
    float4 a0 = *(const float4*)&att_s[4 * tc];
    float4 a1 = *(const float4*)&att_s[64 + 4 * tc];
    asv[0]=a0.x; asv[1]=a0.y; asv[2]=a0.z; asv[3]=a0.w;
    asv[4]=a1.x; asv[5]=a1.y; asv[6]=a1.z; asv[7]=a1.w;
    float4 b0 = *(const float4*)&att_d[4 * tc];
    float4 b1 = *(const float4*)&att_d[64 + 4 * tc];
    adv[0]=b0.x; adv[1]=b0.y; adv[2]=b0.z; adv[3]=b0.w;
    adv[4]=b1.x; adv[5]=b1.y; adv[6]=b1.z; adv[7]=b1.w;
  }
#pragma unroll
  for (int i = 0; i < 4; ++i) {
    int r = rbase + 4 * tr + i;
    float ps = 0.f, pd = 0.f;
#pragma unroll
    for (int j = 0; j < 8; ++j) {
      ps = fmaf(acc[i][j], asv[j], ps);
      pd = fmaf(acc[i][j], adv[j], pd);
    }
#pragma unroll
    for (int o = 1; o < 16; o <<= 1) {
      ps += __shfl_xor(ps, o);
      pd += __shfl_xor(pd, o);
    }
    if (r < NND) {
      if (tc == 0) { a_s[r] = ps; a_d[r] = pd; }
      unsigned p0 = f2bf(acc[i][0]) | (f2bf(acc[i][1]) << 16);
      unsigned p1 = f2bf(acc[i][2]) | (f2bf(acc[i][3]) << 16);
      unsigned p2 = f2bf(acc[i][4]) | (f2bf(acc[i][5]) << 16);
      unsigned p3 = f2bf(acc[i][6]) | (f2bf(acc[i][7]) << 16);
      *(uint2*)&h_bf[(size_t)r * 64 + 2 * tc] = make_uint2(p0, p1);
      *(uint2*)&h_bf[(size_t)r * 64 + 32 + 2 * tc] = make_uint2(p2, p3);
    }
  }
}

// ---------------- radix partition pass 1: per-block 256-bucket histogram ----------------
__global__ __launch_bounds__(1024) void k_hist(const int* __restrict__ ei,
                                               int* __restrict__ hist) {
  __shared__ int hcnt[256];
  const int t = threadIdx.x;
  if (t < 256) hcnt[t] = 0;
  __syncthreads();
  const int base = blockIdx.x * PEB;
#pragma unroll
  for (int i = 0; i < PEB / 1024; ++i) {
    int e = base + i * 1024 + t;
    if (e < ET) {
      int d = (e < NE) ? ei[NE + e] : (e - NE);
      atomicAdd(&hcnt[d >> 9], 1);
    }
  }
  __syncthreads();
  if (t < 256) hist[blockIdx.x * 256 + t] = hcnt[t];
}

// ---------------- pass 2: hist -> absolute chunk offsets; bucket ranges ----------------
__global__ __launch_bounds__(256) void k_hoff(int* __restrict__ hist,
                                              int* __restrict__ bkoff,
                                              int* __restrict__ bkcnt) {
  __shared__ int sm[2][256];
  const int t = threadIdx.x;   // bucket
  int run = 0;
  for (int b = 0; b < PBLK; ++b) {
    int v = hist[b * 256 + t];
    hist[b * 256 + t] = run;
    run += v;
  }
  sm[0][t] = run;
  __syncthreads();
  int c = 0;
  for (int o = 1; o < 256; o <<= 1) {
    int val = sm[c][t];
    if (t >= o) val += sm[c][t - o];
    sm[c ^ 1][t] = val;
    c ^= 1;
    __syncthreads();
  }
  int bstart = sm[c][t] - run;
  bkoff[t] = bstart;
  bkcnt[t] = run;
  for (int b = 0; b < PBLK; ++b) hist[b * 256 + t] += bstart;
}

// ---------------- pass 3: write (src,dst) bucket-major, contiguous chunks ----------------
__global__ __launch_bounds__(1024) void k_part(const int* __restrict__ ei,
                                               const int* __restrict__ hist,
                                               uint2* __restrict__ part) {
  __shared__ int hcur[256];
  const int t = threadIdx.x;
  if (t < 256) hcur[t] = hist[blockIdx.x * 256 + t];
  __syncthreads();
  const int base = blockIdx.x * PEB;
#pragma unroll
  for (int i = 0; i < PEB / 1024; ++i) {
    int e = base + i * 1024 + t;
    if (e < ET) {
      int s, d;
      if (e < NE) { s = ei[e]; d = ei[NE + e]; } else { s = e - NE; d = s; }
      int pos = atomicAdd(&hcur[d >> 9], 1);
      part[pos] = make_uint2((unsigned)s, (unsigned)d);
    }
  }
}

// ---------------- per-bucket degree count (LDS, one block per bucket) ----------------
__global__ __launch_bounds__(256) void k_bdeg(const uint2* __restrict__ part,
                                              const int* __restrict__ bkoff,
                                              const int* __restrict__ bkcnt,
                                              int* __restrict__ deg) {
  __shared__ int dcnt[512];
  const int t = threadIdx.x;
  const int b = blockIdx.x;
  dcnt[t] = 0; dcnt[t + 256] = 0;
  __syncthreads();
  const int lo = bkoff[b], n = bkcnt[b];
  for (int i = t; i < n; i += 256)
    atomicAdd(&dcnt[part[lo + i].y & 511], 1);
  __syncthreads();
#pragma unroll
  for (int j = t; j < 512; j += 256) {
    int node = b * 512 + j;
    if (node < NND) deg[node] = dcnt[j];
  }
}

// ---------------- exclusive scan of deg -> off ----------------
__global__ __launch_bounds__(256) void k_scan1(const int* __restrict__ deg,
                                               int* __restrict__ off,
                                               int* __restrict__ bsum) {
  __shared__ int sm[2][256];
  int t = threadIdx.x;
  int i = blockIdx.x * 256 + t;
  int v = (i < NND) ? deg[i] : 0;
  sm[0][t] = v;
  __syncthreads();
  int c = 0;
  for (int o = 1; o < 256; o <<= 1) {
    int val = sm[c][t];
    if (t >= o) val += sm[c][t - o];
    sm[c ^ 1][t] = val;
    c ^= 1;
    __syncthreads();
  }
  int incl = sm[c][t];
  if (i < NND) off[i] = incl - v;
  if (t == 255) bsum[blockIdx.x] = incl;
}

__global__ __launch_bounds__(512) void k_scan2(int* __restrict__ bsum) {
  __shared__ int sm[2][512];
  const int NB = 391;
  int t = threadIdx.x;
  int v = (t < NB) ? bsum[t] : 0;
  sm[0][t] = v;
  __syncthreads();
  int c = 0;
  for (int o = 1; o < 512; o <<= 1) {
    int val = sm[c][t];
    if (t >= o) val += sm[c][t - o];
    sm[c ^ 1][t] = val;
    c ^= 1;
    __syncthreads();
  }
  if (t < NB) bsum[t] = sm[c][t] - v;
}

__global__ void k_scan3(const int* __restrict__ bsum, int* __restrict__ off) {
  int i = blockIdx.x * 256 + threadIdx.x;
  if (i < NND) off[i] += bsum[blockIdx.x];
}

// ---------------- per-bucket exact scatter (LDS cursors, one block per bucket) --------
__global__ __launch_bounds__(256) void k_bscat(const uint2* __restrict__ part,
                                               const int* __restrict__ bkoff,
                                               const int* __restrict__ bkcnt,
                                               const int* __restrict__ off,
                                               int* __restrict__ esrc) {
  __shared__ int curl[512];
  const int t = threadIdx.x;
  const int b = blockIdx.x;
#pragma unroll
  for (int j = t; j < 512; j += 256) {
    int node = b * 512 + j;
    curl[j] = (node < NND) ? off[node] : 0;
  }
  __syncthreads();
  const int lo = bkoff[b], n = bkcnt[b];
  for (int i = t; i < n; i += 256) {
    uint2 e = part[lo + i];
    int pos = atomicAdd(&curl[e.y & 511], 1);
    esrc[pos] = (int)e.x;
  }
}

// ---------------- single-pass softmax-aggregate + silu ----------------
__global__ __launch_bounds__(256) void k_agg(const int* __restrict__ off,
                                             const int* __restrict__ deg,
                                             const int* __restrict__ esrc,
                                             const float* __restrict__ a_s,
                                             const float* __restrict__ a_d,
                                             const unsigned* __restrict__ hb,
                                             const float* __restrict__ bias,
                                             unsigned* __restrict__ gnn) {
  int wid = (blockIdx.x * 256 + threadIdx.x) >> 6;
  int lane = threadIdx.x & 63;
  if (wid >= NND) return;
  const int grp = lane >> 4;
  const int lc  = lane & 15;
  int start = off[wid];
  int ne = deg[wid];
  float adn = a_d[wid];
  float acc[8] = {};
  float ssum = 0.f;
  for (int base = 0; base < ne; base += 64) {
    int i = base + lane;
    float ev = 0.f;
    int src = 0;
    if (i < ne) {
      src = esrc[start + i];
      float e = a_s[src] + adn;
      e = (e > 0.f) ? e : NEG * e;
      ev = __expf(e);
    }
    ssum += ev;
    int cnt = min(64, ne - base);
    for (int jj = 0; jj < cnt; jj += 4) {
      int idx = jj + grp;
      float p  = __shfl(ev, idx);
      int   sj = __shfl(src, idx);
      uint4 u = *((const uint4*)(hb + ((size_t)sj << 6)) + lc);
      acc[0] = fmaf(p, bflo(u.x), acc[0]);
      acc[1] = fmaf(p, bfhi(u.x), acc[1]);
      acc[2] = fmaf(p, bflo(u.y), acc[2]);
      acc[3] = fmaf(p, bfhi(u.y), acc[3]);
      acc[4] = fmaf(p, bflo(u.z), acc[4]);
      acc[5] = fmaf(p, bfhi(u.z), acc[5]);
      acc[6] = fmaf(p, bflo(u.w), acc[6]);
      acc[7] = fmaf(p, bfhi(u.w), acc[7]);
    }
  }
  for (int o = 32; o; o >>= 1) ssum += __shfl_xor(ssum, o);
#pragma unroll
  for (int r = 0; r < 8; ++r) {
    acc[r] += __shfl_xor(acc[r], 16);
    acc[r] += __shfl_xor(acc[r], 32);
  }
  if (grp == 0) {
    float inv = 1.f / ssum;
    float4 b0 = *(const float4*)&bias[lc * 8];
    float4 b1 = *(const float4*)&bias[lc * 8 + 4];
    float bb[8] = {b0.x, b0.y, b0.z, b0.w, b1.x, b1.y, b1.z, b1.w};
    float g[8];
#pragma unroll
    for (int r = 0; r < 8; ++r) {
      float v = acc[r] * inv + bb[r];
      g[r] = v / (1.f + __expf(-v));
    }
    unsigned w0 = f2bf(g[0]) | (f2bf(g[1]) << 16);
    unsigned w1 = f2bf(g[2]) | (f2bf(g[3]) << 16);
    unsigned w2 = f2bf(g[4]) | (f2bf(g[5]) << 16);
    unsigned w3 = f2bf(g[6]) | (f2bf(g[7]) << 16);
    *(uint4*)&gnn[(size_t)wid * 64 + lc * 4] = make_uint4(w0, w1, w2, w3);
  }
}

// ---------------- per-graph mean pool (batch sorted, run accumulation) ----------------
__global__ __launch_bounds__(256) void k_pool(const unsigned* __restrict__ gnn,
                                              const int* __restrict__ batch,
                                              float* __restrict__ pooled,
                                              float* __restrict__ cnt) {
  int t = threadIdx.x;
  int j2 = t & 63, strm = t >> 6;
  int base = blockIdx.x * 256;
  float ax = 0.f, ay = 0.f, c = 0.f;
  int curb = -1;
  for (int i = 0; i < 64; ++i) {
    int n = base + strm + i * 4;
    if (n >= NND) break;
    int b = batch[n];
    if (b != curb) {
      if (curb >= 0) {
        atomicAdd(&pooled[curb * HD + 2 * j2], ax);
        atomicAdd(&pooled[curb * HD + 2 * j2 + 1], ay);
        if (j2 == 0) atomicAdd(&cnt[curb], c);
      }
      curb = b; ax = 0.f; ay = 0.f; c = 0.f;
    }
    unsigned u = gnn[(size_t)n * 64 + j2];
    ax += bflo(u);
    ay += bfhi(u);
    c += 1.f;
  }
  if (curb >= 0) {
    atomicAdd(&pooled[curb * HD + 2 * j2], ax);
    atomicAdd(&pooled[curb * HD + 2 * j2 + 1], ay);
    if (j2 == 0) atomicAdd(&cnt[curb], c);
  }
}

// ---------------- final ----------------
__global__ void k_final(const float* __restrict__ pooled,
                        const float* __restrict__ cnt,
                        const float* __restrict__ fin_w,
                        const float* __restrict__ fin_b,
                        float* __restrict__ out) {
  int w = threadIdx.x >> 6, lane = threadIdx.x & 63;
  for (int g = w; g < NGR; g += 4) {
    float2 pv = *(const float2*)&pooled[g * HD + lane * 2];
    float2 fw = *(const float2*)&fin_w[lane * 2];
    float s = pv.x * fw.x + pv.y * fw.y;
    for (int o = 32; o; o >>= 1) s += __shfl_xor(s, o);
    if (lane == 0) out[g] = s / fmaxf(cnt[g], 1.f) + fin_b[0];
  }
}

extern "C" void kernel_launch(void* const* d_in, const int* in_sizes, int n_in,
                              void* d_out, int out_size, void* d_ws, size_t ws_size,
                              hipStream_t stream) {
  const float* x       = (const float*)d_in[0];
  const int*   ei      = (const int*)d_in[1];
  const int*   batch   = (const int*)d_in[2];
  const float* W       = (const float*)d_in[3];
  const float* att_src = (const float*)d_in[4];
  const float* att_dst = (const float*)d_in[5];
  const float* bias    = (const float*)d_in[6];
  const float* fin_w   = (const float*)d_in[7];
  const float* fin_b   = (const float*)d_in[8];
  float* out = (float*)d_out;

  float*    a_s  = (float*)d_ws;                       // NND
  float*    a_d  = a_s + NND;                          // NND
  unsigned* h_bf = (unsigned*)(a_d + NND);             // NND*64
  unsigned* gnn  = h_bf + (size_t)NND * 64;            // NND*64
  uint2*    part = (uint2*)(gnn + (size_t)NND * 64);   // ET (8B, offset is 8B-aligned)
  int*      esrc = (int*)(part + ET);                  // ET
  int*      off  = esrc + ET;                          // NND
  int*      deg  = off + NND;                          // NND
  int*      bsum = deg + NND;                          // 512
  int*      hist = bsum + 512;                         // PBLK*256
  int*      bkoff= hist + PBLK * 256;                  // 256
  int*      bkcnt= bkoff + 256;                        // 256
  float*  pooled = (float*)(bkcnt + 256);              // NGR*HD
  float*    cnt  = pooled + NGR * HD;                  // NGR

  hipMemsetAsync(pooled, 0, (size_t)(NGR * HD + NGR) * 4, stream);

  k_gemm <<<(NND + 127) / 128, 512, 0, stream>>>(x, W, att_src, att_dst, h_bf, a_s, a_d);
  k_hist <<<PBLK, 1024, 0, stream>>>(ei, hist);
  k_hoff <<<1, 256, 0, stream>>>(hist, bkoff, bkcnt);
  k_part <<<PBLK, 1024, 0, stream>>>(ei, hist, part);
  k_bdeg <<<NBK, 256, 0, stream>>>(part, bkoff, bkcnt, deg);
  k_scan1<<<391, 256, 0, stream>>>(deg, off, bsum);
  k_scan2<<<1, 512, 0, stream>>>(bsum);
  k_scan3<<<391, 256, 0, stream>>>(bsum, off);
  k_bscat<<<NBK, 256, 0, stream>>>(part, bkoff, bkcnt, off, esrc);
  k_agg  <<<25000, 256, 0, stream>>>(off, deg, esrc, a_s, a_d, h_bf, bias, gnn);
  k_pool <<<391, 256, 0, stream>>>(gnn, batch, pooled, cnt);
  k_final<<<1, 256, 0, stream>>>(pooled, cnt, fin_w, fin_b, out);
}

// Round 6
// 348.196 us; speedup vs baseline: 1.7524x; 1.0862x over previous
//
#include <hip/hip_runtime.h>

#define NND 100000
#define NE  1600000
#define ET  (NE + NND)      // 1,700,000 edges incl. self loops
#define HD  128
#define NGR 64
#define NEG 0.2f

#define PEB   16384                     // edges per partition block
#define PBLK  ((ET + PEB - 1) / PEB)    // 104
#define NBK   ((NND + 511) / 512)       // 196 buckets of 512 nodes

typedef __attribute__((ext_vector_type(8))) short short8;
typedef __attribute__((ext_vector_type(4))) float f32x4;

__device__ __forceinline__ unsigned f2bf(float x) {
  unsigned u = __builtin_bit_cast(unsigned, x);
  return (u + 0x7fffu + ((u >> 16) & 1u)) >> 16;   // RNE, finite inputs
}
__device__ __forceinline__ float bflo(unsigned u) { return __builtin_bit_cast(float, u << 16); }
__device__ __forceinline__ float bfhi(unsigned u) { return __builtin_bit_cast(float, u & 0xffff0000u); }

// ---------------- W transpose to bf16 [col][k] (one-off, 32 KB, L2-resident) --------
__global__ void k_wt(const float* __restrict__ W, unsigned short* __restrict__ WT) {
  int t = blockIdx.x * 256 + threadIdx.x;   // 0..16383
  int c = t >> 7, k = t & 127;
  WT[t] = (unsigned short)f2bf(W[k * HD + c]);
}

// ---------------- GEMM: h = x @ W via bf16 MFMA, fused a_s/a_d dots ----------------
// no LDS: A-frags converted in-register from global x; B-frags from L2-resident WT.
// frag maps (m89-verified family): A row=l%16,k=(l/16)*8+e; B col=l%16 same k;
// D col=l%16, row=(l/16)*4+r.
__global__ __launch_bounds__(256) void k_gemm(const float* __restrict__ x,
                                              const unsigned short* __restrict__ WT,
                                              const float* __restrict__ att_s,
                                              const float* __restrict__ att_d,
                                              unsigned* __restrict__ h_bf,
                                              float* __restrict__ a_s,
                                              float* __restrict__ a_d) {
  const int t = threadIdx.x;
  const int wv = t >> 6, l = t & 63;
  const int lr = l & 15, lk = l >> 4;
  const int arow = blockIdx.x * 64 + wv * 16 + lr;     // A-row this lane feeds
  const bool av = arow < NND;
  const float* xrow = x + (size_t)(av ? arow : 0) * HD;
  f32x4 acc[8];
#pragma unroll
  for (int j = 0; j < 8; ++j) acc[j] = (f32x4){0.f, 0.f, 0.f, 0.f};
#pragma unroll 1
  for (int s = 0; s < 4; ++s) {
    const int k0 = s * 32 + lk * 8;
    float4 x0 = av ? *(const float4*)&xrow[k0]     : make_float4(0.f, 0.f, 0.f, 0.f);
    float4 x1 = av ? *(const float4*)&xrow[k0 + 4] : make_float4(0.f, 0.f, 0.f, 0.f);
    short8 af;
    af[0] = (short)f2bf(x0.x); af[1] = (short)f2bf(x0.y);
    af[2] = (short)f2bf(x0.z); af[3] = (short)f2bf(x0.w);
    af[4] = (short)f2bf(x1.x); af[5] = (short)f2bf(x1.y);
    af[6] = (short)f2bf(x1.z); af[7] = (short)f2bf(x1.w);
#pragma unroll
    for (int j = 0; j < 8; ++j) {
      short8 bf8 = *(const short8*)&WT[(size_t)(j * 16 + lr) * HD + k0];
      acc[j] = __builtin_amdgcn_mfma_f32_16x16x32_bf16(af, bf8, acc[j], 0, 0, 0);
    }
  }
  // epilogue: att dots (reduce over the 16 col-lanes)
  float asv[8], adv[8];
#pragma unroll
  for (int j = 0; j < 8; ++j) { asv[j] = att_s[j * 16 + lr]; adv[j] = att_d[j * 16 + lr]; }
  float pa[4] = {0.f, 0.f, 0.f, 0.f}, pd[4] = {0.f, 0.f, 0.f, 0.f};
#pragma unroll
  for (int j = 0; j < 8; ++j)
#pragma unroll
    for (int r = 0; r < 4; ++r) {
      pa[r] = fmaf(acc[j][r], asv[j], pa[r]);
      pd[r] = fmaf(acc[j][r], adv[j], pd[r]);
    }
#pragma unroll
  for (int o = 1; o < 16; o <<= 1)
#pragma unroll
    for (int r = 0; r < 4; ++r) {
      pa[r] += __shfl_xor(pa[r], o);
      pd[r] += __shfl_xor(pd[r], o);
    }
  const int rbase = blockIdx.x * 64 + wv * 16 + lk * 4;   // D-rows this lane owns
#pragma unroll
  for (int r = 0; r < 4; ++r) {
    int row = rbase + r;
    if (row < NND && lr == 0) { a_s[row] = pa[r]; a_d[row] = pd[r]; }
  }
  // h writes: pack col pairs via lane-pair shfl
#pragma unroll
  for (int j = 0; j < 8; ++j)
#pragma unroll
    for (int r = 0; r < 4; ++r) {
      float v = acc[j][r];
      float vn = __shfl_xor(v, 1);
      int row = rbase + r;
      if ((lr & 1) == 0 && row < NND) {
        unsigned w = f2bf(v) | (f2bf(vn) << 16);
        h_bf[(size_t)row * 64 + ((j * 16 + lr) >> 1)] = w;
      }
    }
}

// ---------------- radix partition pass 1: per-block 256-bucket histogram ----------------
__global__ __launch_bounds__(1024) void k_hist(const int* __restrict__ ei,
                                               int* __restrict__ hist) {
  __shared__ int hcnt[256];
  const int t = threadIdx.x;
  if (t < 256) hcnt[t] = 0;
  __syncthreads();
  const int base = blockIdx.x * PEB;
#pragma unroll
  for (int i = 0; i < PEB / 1024; ++i) {
    int e = base + i * 1024 + t;
    if (e < ET) {
      int d = (e < NE) ? ei[NE + e] : (e - NE);
      atomicAdd(&hcnt[d >> 9], 1);
    }
  }
  __syncthreads();
  if (t < 256) hist[blockIdx.x * 256 + t] = hcnt[t];
}

// ---------------- pass 2: hist -> absolute chunk offsets; bucket ranges ----------------
__global__ __launch_bounds__(256) void k_hoff(int* __restrict__ hist,
                                              int* __restrict__ bkoff,
                                              int* __restrict__ bkcnt) {
  __shared__ int sm[2][256];
  const int t = threadIdx.x;   // bucket
  int run = 0;
  for (int b = 0; b < PBLK; ++b) {
    int v = hist[b * 256 + t];
    hist[b * 256 + t] = run;
    run += v;
  }
  sm[0][t] = run;
  __syncthreads();
  int c = 0;
  for (int o = 1; o < 256; o <<= 1) {
    int val = sm[c][t];
    if (t >= o) val += sm[c][t - o];
    sm[c ^ 1][t] = val;
    c ^= 1;
    __syncthreads();
  }
  int bstart = sm[c][t] - run;
  bkoff[t] = bstart;
  bkcnt[t] = run;
  for (int b = 0; b < PBLK; ++b) hist[b * 256 + t] += bstart;
}

// ---------------- pass 3: write (src,dst) bucket-major, contiguous chunks ----------------
__global__ __launch_bounds__(1024) void k_part(const int* __restrict__ ei,
                                               const int* __restrict__ hist,
                                               uint2* __restrict__ part) {
  __shared__ int hcur[256];
  const int t = threadIdx.x;
  if (t < 256) hcur[t] = hist[blockIdx.x * 256 + t];
  __syncthreads();
  const int base = blockIdx.x * PEB;
#pragma unroll
  for (int i = 0; i < PEB / 1024; ++i) {
    int e = base + i * 1024 + t;
    if (e < ET) {
      int s, d;
      if (e < NE) { s = ei[e]; d = ei[NE + e]; } else { s = e - NE; d = s; }
      int pos = atomicAdd(&hcur[d >> 9], 1);
      part[pos] = make_uint2((unsigned)s, (unsigned)d);
    }
  }
}

// ---------------- per-bucket degree count (LDS, one block per bucket) ----------------
__global__ __launch_bounds__(256) void k_bdeg(const uint2* __restrict__ part,
                                              const int* __restrict__ bkoff,
                                              const int* __restrict__ bkcnt,
                                              int* __restrict__ deg) {
  __shared__ int dcnt[512];
  const int t = threadIdx.x;
  const int b = blockIdx.x;
  dcnt[t] = 0; dcnt[t + 256] = 0;
  __syncthreads();
  const int lo = bkoff[b], n = bkcnt[b];
  for (int i = t; i < n; i += 256)
    atomicAdd(&dcnt[part[lo + i].y & 511], 1);
  __syncthreads();
#pragma unroll
  for (int j = t; j < 512; j += 256) {
    int node = b * 512 + j;
    if (node < NND) deg[node] = dcnt[j];
  }
}

// ---------------- exclusive scan of deg -> off ----------------
__global__ __launch_bounds__(256) void k_scan1(const int* __restrict__ deg,
                                               int* __restrict__ off,
                                               int* __restrict__ bsum) {
  __shared__ int sm[2][256];
  int t = threadIdx.x;
  int i = blockIdx.x * 256 + t;
  int v = (i < NND) ? deg[i] : 0;
  sm[0][t] = v;
  __syncthreads();
  int c = 0;
  for (int o = 1; o < 256; o <<= 1) {
    int val = sm[c][t];
    if (t >= o) val += sm[c][t - o];
    sm[c ^ 1][t] = val;
    c ^= 1;
    __syncthreads();
  }
  int incl = sm[c][t];
  if (i < NND) off[i] = incl - v;
  if (t == 255) bsum[blockIdx.x] = incl;
}

__global__ __launch_bounds__(512) void k_scan2(int* __restrict__ bsum) {
  __shared__ int sm[2][512];
  const int NB = 391;
  int t = threadIdx.x;
  int v = (t < NB) ? bsum[t] : 0;
  sm[0][t] = v;
  __syncthreads();
  int c = 0;
  for (int o = 1; o < 512; o <<= 1) {
    int val = sm[c][t];
    if (t >= o) val += sm[c][t - o];
    sm[c ^ 1][t] = val;
    c ^= 1;
    __syncthreads();
  }
  if (t < NB) bsum[t] = sm[c][t] - v;
}

__global__ void k_scan3(const int* __restrict__ bsum, int* __restrict__ off) {
  int i = blockIdx.x * 256 + threadIdx.x;
  if (i < NND) off[i] += bsum[blockIdx.x];
}

// ---------------- per-bucket exact scatter (LDS cursors, one block per bucket) --------
__global__ __launch_bounds__(256) void k_bscat(const uint2* __restrict__ part,
                                               const int* __restrict__ bkoff,
                                               const int* __restrict__ bkcnt,
                                               const int* __restrict__ off,
                                               int* __restrict__ esrc) {
  __shared__ int curl[512];
  const int t = threadIdx.x;
  const int b = blockIdx.x;
#pragma unroll
  for (int j = t; j < 512; j += 256) {
    int node = b * 512 + j;
    curl[j] = (node < NND) ? off[node] : 0;
  }
  __syncthreads();
  const int lo = bkoff[b], n = bkcnt[b];
  for (int i = t; i < n; i += 256) {
    uint2 e = part[lo + i];
    int pos = atomicAdd(&curl[e.y & 511], 1);
    esrc[pos] = (int)e.x;
  }
}

// ---------------- single-pass softmax-aggregate + silu ----------------
__global__ __launch_bounds__(256) void k_agg(const int* __restrict__ off,
                                             const int* __restrict__ deg,
                                             const int* __restrict__ esrc,
                                             const float* __restrict__ a_s,
                                             const float* __restrict__ a_d,
                                             const unsigned* __restrict__ hb,
                                             const float* __restrict__ bias,
                                             unsigned* __restrict__ gnn) {
  int wid = (blockIdx.x * 256 + threadIdx.x) >> 6;
  int lane = threadIdx.x & 63;
  if (wid >= NND) return;
  const int grp = lane >> 4;
  const int lc  = lane & 15;
  int start = off[wid];
  int ne = deg[wid];
  float adn = a_d[wid];
  float acc[8] = {};
  float ssum = 0.f;
  for (int base = 0; base < ne; base += 64) {
    int i = base + lane;
    float ev = 0.f;
    int src = 0;
    if (i < ne) {
      src = esrc[start + i];
      float e = a_s[src] + adn;
      e = (e > 0.f) ? e : NEG * e;
      ev = __expf(e);
    }
    ssum += ev;
    int cnt = min(64, ne - base);
    for (int jj = 0; jj < cnt; jj += 4) {
      int idx = jj + grp;
      float p  = __shfl(ev, idx);
      int   sj = __shfl(src, idx);
      uint4 u = *((const uint4*)(hb + ((size_t)sj << 6)) + lc);
      acc[0] = fmaf(p, bflo(u.x), acc[0]);
      acc[1] = fmaf(p, bfhi(u.x), acc[1]);
      acc[2] = fmaf(p, bflo(u.y), acc[2]);
      acc[3] = fmaf(p, bfhi(u.y), acc[3]);
      acc[4] = fmaf(p, bflo(u.z), acc[4]);
      acc[5] = fmaf(p, bfhi(u.z), acc[5]);
      acc[6] = fmaf(p, bflo(u.w), acc[6]);
      acc[7] = fmaf(p, bfhi(u.w), acc[7]);
    }
  }
  for (int o = 32; o; o >>= 1) ssum += __shfl_xor(ssum, o);
#pragma unroll
  for (int r = 0; r < 8; ++r) {
    acc[r] += __shfl_xor(acc[r], 16);
    acc[r] += __shfl_xor(acc[r], 32);
  }
  if (grp == 0) {
    float inv = 1.f / ssum;
    float4 b0 = *(const float4*)&bias[lc * 8];
    float4 b1 = *(const float4*)&bias[lc * 8 + 4];
    float bb[8] = {b0.x, b0.y, b0.z, b0.w, b1.x, b1.y, b1.z, b1.w};
    float g[8];
#pragma unroll
    for (int r = 0; r < 8; ++r) {
      float v = acc[r] * inv + bb[r];
      g[r] = v / (1.f + __expf(-v));
    }
    unsigned w0 = f2bf(g[0]) | (f2bf(g[1]) << 16);
    unsigned w1 = f2bf(g[2]) | (f2bf(g[3]) << 16);
    unsigned w2 = f2bf(g[4]) | (f2bf(g[5]) << 16);
    unsigned w3 = f2bf(g[6]) | (f2bf(g[7]) << 16);
    *(uint4*)&gnn[(size_t)wid * 64 + lc * 4] = make_uint4(w0, w1, w2, w3);
  }
}

// ---------------- per-graph mean pool (batch sorted, run accumulation) ----------------
__global__ __launch_bounds__(256) void k_pool(const unsigned* __restrict__ gnn,
                                              const int* __restrict__ batch,
                                              float* __restrict__ pooled,
                                              float* __restrict__ cnt) {
  int t = threadIdx.x;
  int j2 = t & 63, strm = t >> 6;
  int base = blockIdx.x * 256;
  float ax = 0.f, ay = 0.f, c = 0.f;
  int curb = -1;
  for (int i = 0; i < 64; ++i) {
    int n = base + strm + i * 4;
    if (n >= NND) break;
    int b = batch[n];
    if (b != curb) {
      if (curb >= 0) {
        atomicAdd(&pooled[curb * HD + 2 * j2], ax);
        atomicAdd(&pooled[curb * HD + 2 * j2 + 1], ay);
        if (j2 == 0) atomicAdd(&cnt[curb], c);
      }
      curb = b; ax = 0.f; ay = 0.f; c = 0.f;
    }
    unsigned u = gnn[(size_t)n * 64 + j2];
    ax += bflo(u);
    ay += bfhi(u);
    c += 1.f;
  }
  if (curb >= 0) {
    atomicAdd(&pooled[curb * HD + 2 * j2], ax);
    atomicAdd(&pooled[curb * HD + 2 * j2 + 1], ay);
    if (j2 == 0) atomicAdd(&cnt[curb], c);
  }
}

// ---------------- final ----------------
__global__ void k_final(const float* __restrict__ pooled,
                        const float* __restrict__ cnt,
                        const float* __restrict__ fin_w,
                        const float* __restrict__ fin_b,
                        float* __restrict__ out) {
  int w = threadIdx.x >> 6, lane = threadIdx.x & 63;
  for (int g = w; g < NGR; g += 4) {
    float2 pv = *(const float2*)&pooled[g * HD + lane * 2];
    float2 fw = *(const float2*)&fin_w[lane * 2];
    float s = pv.x * fw.x + pv.y * fw.y;
    for (int o = 32; o; o >>= 1) s += __shfl_xor(s, o);
    if (lane == 0) out[g] = s / fmaxf(cnt[g], 1.f) + fin_b[0];
  }
}

extern "C" void kernel_launch(void* const* d_in, const int* in_sizes, int n_in,
                              void* d_out, int out_size, void* d_ws, size_t ws_size,
                              hipStream_t stream) {
  const float* x       = (const float*)d_in[0];
  const int*   ei      = (const int*)d_in[1];
  const int*   batch   = (const int*)d_in[2];
  const float* W       = (const float*)d_in[3];
  const float* att_src = (const float*)d_in[4];
  const float* att_dst = (const float*)d_in[5];
  const float* bias    = (const float*)d_in[6];
  const float* fin_w   = (const float*)d_in[7];
  const float* fin_b   = (const float*)d_in[8];
  float* out = (float*)d_out;

  float*    a_s  = (float*)d_ws;                       // NND
  float*    a_d  = a_s + NND;                          // NND
  unsigned* h_bf = (unsigned*)(a_d + NND);             // NND*64
  unsigned* gnn  = h_bf + (size_t)NND * 64;            // NND*64
  uint2*    part = (uint2*)(gnn + (size_t)NND * 64);   // ET (8B-aligned offset)
  int*      esrc = (int*)(part + ET);                  // ET
  int*      off  = esrc + ET;                          // NND
  int*      deg  = off + NND;                          // NND
  int*      bsum = deg + NND;                          // 512
  int*      hist = bsum + 512;                         // PBLK*256
  int*      bkoff= hist + PBLK * 256;                  // 256
  int*      bkcnt= bkoff + 256;                        // 256
  float*  pooled = (float*)(bkcnt + 256);              // NGR*HD
  float*    cnt  = pooled + NGR * HD;                  // NGR
  unsigned short* WT = (unsigned short*)(cnt + NGR);   // 128*128 bf16 (16B-aligned)

  hipMemsetAsync(pooled, 0, (size_t)(NGR * HD + NGR) * 4, stream);

  k_wt   <<<64, 256, 0, stream>>>(W, WT);
  k_gemm <<<(NND + 63) / 64, 256, 0, stream>>>(x, WT, att_src, att_dst, h_bf, a_s, a_d);
  k_hist <<<PBLK, 1024, 0, stream>>>(ei, hist);
  k_hoff <<<1, 256, 0, stream>>>(hist, bkoff, bkcnt);
  k_part <<<PBLK, 1024, 0, stream>>>(ei, hist, part);
  k_bdeg <<<NBK, 256, 0, stream>>>(part, bkoff, bkcnt, deg);
  k_scan1<<<391, 256, 0, stream>>>(deg, off, bsum);
  k_scan2<<<1, 512, 0, stream>>>(bsum);
  k_scan3<<<391, 256, 0, stream>>>(bsum, off);
  k_bscat<<<NBK, 256, 0, stream>>>(part, bkoff, bkcnt, off, esrc);
  k_agg  <<<25000, 256, 0, stream>>>(off, deg, esrc, a_s, a_d, h_bf, bias, gnn);
  k_pool <<<391, 256, 0, stream>>>(gnn, batch, pooled, cnt);
  k_final<<<1, 256, 0, stream>>>(pooled, cnt, fin_w, fin_b, out);
}